// Round 5
// baseline (562.477 us; speedup 1.0000x reference)
//
#include <hip/hip_runtime.h>
#include <hip/hip_bf16.h>
#include <cstdint>
#include <cstddef>

// Problem constants (HybridMoE): T tokens, H hidden, I intermediate, E experts, top-2.
#define TT 2048
#define HH 2048
#define II 1408
#define EE 8
#define MAXROWS 5120   // sum of 128-padded per-expert counts <= 4096 + 8*127

typedef unsigned short u16;
typedef __attribute__((ext_vector_type(8))) __bf16 bf16x8;   // MFMA A/B operand (4 VGPRs)
typedef __attribute__((ext_vector_type(4))) float f32x4;     // MFMA C/D operand

typedef const __attribute__((address_space(1))) uint32_t* gas1_t;
typedef __attribute__((address_space(3))) uint32_t* las3_t;

// counted waitcnt (N = outstanding vector-mem ops allowed to remain)
#define VM_WAIT(N) asm volatile("s_waitcnt vmcnt(" #N ")" ::: "memory")
#define IR_FENCE() asm volatile("" ::: "memory")

// ---------- helpers ----------
__device__ __forceinline__ float bf2f(u16 b) {
    return __uint_as_float(((uint32_t)b) << 16);
}
__device__ __forceinline__ u16 f2bf(float x) {   // round-to-nearest-even
    uint32_t u = __float_as_uint(x);
    u += 0x7fffu + ((u >> 16) & 1u);
    return (u16)(u >> 16);
}

// ---------- dtype sniff: inputs f32 (flag=1) or bf16 (flag=0); also zeroes counts ----------
__global__ void k_sniff(const u16* __restrict__ raw, int* __restrict__ flag,
                        int* __restrict__ counts) {
    __shared__ int cnt;
    if (threadIdx.x < EE) counts[threadIdx.x] = 0;
    if (threadIdx.x == 0) cnt = 0;
    __syncthreads();
    int w = 0;
    for (int i = threadIdx.x; i < 4096; i += 256) {
        u16 x = raw[i];
        if (x & 0x7fff) {
            int ex = (x >> 7) & 0xff;
            if (ex == 0xff || ex < 100 || ex > 140) ++w;
        }
    }
    atomicAdd(&cnt, w);
    __syncthreads();
    if (threadIdx.x == 0) flag[0] = (cnt > 100) ? 1 : 0;
}

// ---------- routing: top-2 softmax -> per-expert token lists + per-token slot map ----------
__global__ void k_routing2(const void* __restrict__ logits, const int* __restrict__ flag,
                           int* __restrict__ counts, int* __restrict__ idx,
                           float* __restrict__ wt, int* __restrict__ slot) {
    int t = blockIdx.x * 256 + threadIdx.x;
    if (t >= TT) return;
    const int f = flag[0];
    float v[EE];
#pragma unroll
    for (int e = 0; e < EE; ++e)
        v[e] = f ? ((const float*)logits)[t * EE + e]
                 : bf2f(((const u16*)logits)[t * EE + e]);
    int i0 = 0; float v0 = v[0];
#pragma unroll
    for (int e = 1; e < EE; ++e) { if (v[e] > v0) { v0 = v[e]; i0 = e; } }
    int i1 = -1; float v1 = -3.4e38f;
#pragma unroll
    for (int e = 0; e < EE; ++e) { if (e != i0 && v[e] > v1) { v1 = v[e]; i1 = e; } }
    float r = __expf(v1 - v0);          // <= 1
    float s = 1.f / (1.f + r);
    int p0 = atomicAdd(&counts[i0], 1);
    idx[i0 * TT + p0] = t; wt[i0 * TT + p0] = s;
    slot[t * 2 + 0] = i0 * TT + p0;
    int p1 = atomicAdd(&counts[i1], 1);
    idx[i1 * TT + p1] = t; wt[i1 * TT + p1] = r * s;
    slot[t * 2 + 1] = i1 * TT + p1;
}

// ---------- offsets: meta[e]=row offset of expert e, meta[8+e]=padded count ----------
__global__ void k_offsets(const int* __restrict__ counts, int* __restrict__ meta) {
    if (threadIdx.x == 0 && blockIdx.x == 0) {
        int off = 0;
        for (int e = 0; e < EE; ++e) {
            int c = counts[e];
            int p = (c + 127) & ~127;
            meta[e] = off; meta[8 + e] = p;
            off += p;
        }
    }
}

// ---------- cast hidden_states to bf16 workspace copy ----------
__global__ void k_cast(const void* __restrict__ src, const int* __restrict__ flag,
                       u16* __restrict__ dst) {
    const int i0 = (blockIdx.x * 256 + threadIdx.x) * 8;
    if (flag[0]) {
        const float* s = (const float*)src;
#pragma unroll
        for (int j = 0; j < 8; ++j) dst[i0 + j] = f2bf(s[i0 + j]);
    } else {
        const u16* s = (const u16*)src;
        *(uint4*)&dst[i0] = *(const uint4*)&s[i0];
    }
}

// ---------- packed transpose per expert: src[R,C] (f32/bf16) -> dst[C,R] bf16 ----------
// 64x64 tile, 256 threads.  Row-pairs packed into u32 (2 bf16 from rows 2rp,2rp+1 at
// col c) stored TT[c][rp]; read side does b64 reads (4 consecutive out cols) ->
// 2x uint4 global stores.  LDS ops/thread: 8 write_b32 + 8 read_b64-equiv, <=4-way.
// (Old version did 16 scalar ds_read_u16 at 8-way conflict per thread.)
__global__ void k_transposeP(const void* __restrict__ src, const int* __restrict__ flag,
                             u16* __restrict__ dst, int R, int C) {
    __shared__ uint32_t TTs[64 * 34];
    const size_t eo = (size_t)blockIdx.z * (size_t)R * (size_t)C;
    const int r0 = blockIdx.y * 64, c0 = blockIdx.x * 64;
    const int tid = threadIdx.x;
    const int f = flag[0];
    const int cg = (tid & 15) * 4;       // col group (4 cols)
    const int rh = tid >> 4;             // 0..15
#pragma unroll
    for (int p = 0; p < 2; ++p) {
        const int rp = rh + 16 * p;      // row-pair index 0..31
        const int r  = 2 * rp;
        const size_t base = eo + (size_t)(r0 + r) * C + c0 + cg;
        uint32_t w0, w1, w2, w3;
        if (f) {
            const float4 v0 = *(const float4*)((const float*)src + base);
            const float4 v1 = *(const float4*)((const float*)src + base + C);
            w0 = (uint32_t)f2bf(v0.x) | ((uint32_t)f2bf(v1.x) << 16);
            w1 = (uint32_t)f2bf(v0.y) | ((uint32_t)f2bf(v1.y) << 16);
            w2 = (uint32_t)f2bf(v0.z) | ((uint32_t)f2bf(v1.z) << 16);
            w3 = (uint32_t)f2bf(v0.w) | ((uint32_t)f2bf(v1.w) << 16);
        } else {
            const ushort4 v0 = *(const ushort4*)((const u16*)src + base);
            const ushort4 v1 = *(const ushort4*)((const u16*)src + base + C);
            w0 = (uint32_t)v0.x | ((uint32_t)v1.x << 16);
            w1 = (uint32_t)v0.y | ((uint32_t)v1.y << 16);
            w2 = (uint32_t)v0.z | ((uint32_t)v1.z << 16);
            w3 = (uint32_t)v0.w | ((uint32_t)v1.w << 16);
        }
        TTs[(cg + 0) * 34 + rp] = w0;
        TTs[(cg + 1) * 34 + rp] = w1;
        TTs[(cg + 2) * 34 + rp] = w2;
        TTs[(cg + 3) * 34 + rp] = w3;
    }
    __syncthreads();
    // out rows c = tid>>2 (one per thread), cols r0+16u..r0+16u+15 (u = tid&3)
    const int c = tid >> 2, u = tid & 3;
    uint32_t o[8];
#pragma unroll
    for (int k = 0; k < 4; ++k) {
        const int rp = 8 * u + 2 * k;
        o[2 * k]     = TTs[c * 34 + rp];
        o[2 * k + 1] = TTs[c * 34 + rp + 1];
    }
    u16* dp = dst + eo + (size_t)(c0 + c) * R + r0 + 16 * u;
    *(uint4*)(dp)     = make_uint4(o[0], o[1], o[2], o[3]);
    *(uint4*)(dp + 8) = make_uint4(o[4], o[5], o[6], o[7]);
}

// ================= GEMM1 sparse (dual), 256 threads / 4 waves =================
// Tile 128m x 64n; 4 waves of 64m x 32n.
// 3-deep counted-vmcnt pipeline: stage(t+2); vmcnt(8); barrier; compute(t); barrier.
// Tile t is waited on TWO iterations after issue (~700-1000cy cover) -> L2/L3
// latency hidden; LDS 49KB still allows 3 blocks/CU (round-2's 3-deep failed only
// because 8-wave/75KB blocks collapsed to 0.7 blocks/CU).
// Grid (e=8, m=16, n=22), blockIdx.x FASTEST in linearization: linear%8==e pins
// expert to XCD; next-fastest y=m -> consecutive same-XCD blocks share the (e,n)
// B-panel (L2-hot 512KB) instead of re-streaming it from L3 16x (the y/z swap:
// all previous rounds were n-fastest despite comments).  A-slab ~2MB L2-resident.
// XOR bank swizzle (round-1: conflicts -> 0).

#define G1_COMPUTE(B) do { \
    __builtin_amdgcn_s_setprio(1); \
    bf16x8 af[4]; \
    _Pragma("unroll") \
    for (int mi = 0; mi < 4; ++mi) \
        af[mi] = *(const bf16x8*)&As[B][(wr + mi * 16 + ln) * 32 + qx]; \
    _Pragma("unroll") \
    for (int ni = 0; ni < 2; ++ni) { \
        bf16x8 bgf = *(const bf16x8*)&Bg[B][(wc + ni * 16 + ln) * 32 + qx]; \
        bf16x8 buf_ = *(const bf16x8*)&Bu[B][(wc + ni * 16 + ln) * 32 + qx]; \
        _Pragma("unroll") \
        for (int mi = 0; mi < 4; ++mi) { \
            accg[mi][ni] = __builtin_amdgcn_mfma_f32_16x16x32_bf16(af[mi], bgf, accg[mi][ni], 0, 0, 0); \
            accu[mi][ni] = __builtin_amdgcn_mfma_f32_16x16x32_bf16(af[mi], buf_, accu[mi][ni], 0, 0, 0); \
        } \
    } \
    __builtin_amdgcn_s_setprio(0); \
} while (0)

#define G1_STAGE(B, KB) do { \
    __builtin_amdgcn_global_load_lds((gas1_t)(pA0 + (KB)), (las3_t)(&As[B][dofs]), 16, 0, 0); \
    __builtin_amdgcn_global_load_lds((gas1_t)(pA1 + (KB)), (las3_t)(&As[B][2048 + dofs]), 16, 0, 0); \
    __builtin_amdgcn_global_load_lds((gas1_t)(pG + (KB)), (las3_t)(&Bg[B][dofs]), 16, 0, 0); \
    __builtin_amdgcn_global_load_lds((gas1_t)(pU + (KB)), (las3_t)(&Bu[B][dofs]), 16, 0, 0); \
} while (0)

__global__ __launch_bounds__(256, 4)
void k_gemm1s(const u16* __restrict__ hs_b,  // [T,H] bf16
              const u16* __restrict__ Wgt,   // [E,I,H] bf16
              const u16* __restrict__ Wut,   // [E,I,H] bf16
              const int* __restrict__ counts,
              const int* __restrict__ meta,
              const int* __restrict__ idx,
              const float* __restrict__ wt,
              u16* __restrict__ act_g) {     // [MAXROWS, I] bf16
    const int e = blockIdx.x;
    const int cnt = counts[e];
    const int pcnt = meta[8 + e];
    const int m0 = blockIdx.y * 128;
    if (m0 >= pcnt) return;
    const int n0 = blockIdx.z * 64;
    const int off = meta[e];
    const int tid = threadIdx.x;
    const int wave = tid >> 6, lane = tid & 63;
    const int ln = lane & 15, q = lane >> 4;
    const int wr = (wave >> 1) * 64;           // 2 m-rows of waves
    const int wc = (wave & 1) * 32;            // 2 n-cols of waves

    __shared__ __align__(16) u16 As[3][128 * 32];
    __shared__ __align__(16) u16 Bg[3][64 * 32];
    __shared__ __align__(16) u16 Bu[3][64 * 32];
    __shared__ int   tokS[128];
    __shared__ float wtS[128];

    if (tid < 128) {
        const int pos = m0 + tid;
        const bool v = pos < cnt;
        tokS[tid] = v ? idx[e * TT + pos] : 0;
        wtS[tid]  = v ? wt[e * TT + pos] : 0.f;
    }
    __syncthreads();   // tokS visible; vmcnt drained -> pipeline starts at 0 outstanding

    // staging geometry: 256 threads x 16B = 4KB per issue.  A tile (128x32=8KB):
    // 2 issues; Bg/Bu tiles (64x32=4KB): 1 issue each.  LDS dest linear, source
    // column XOR-swizzled so read chunk q^((row>>1)&3) returns global chunk q.
    const int srow = tid >> 2;                 // 0..63
    const int csw  = (((tid & 3) ^ ((srow >> 1) & 3))) * 8;
    const u16* pA0 = hs_b + (size_t)tokS[srow] * HH + csw;       // gathered token rows 0..63
    const u16* pA1 = hs_b + (size_t)tokS[srow + 64] * HH + csw;  // rows 64..127
    const u16* pG = Wgt + ((size_t)e * II + n0 + srow) * HH + csw;
    const u16* pU = Wut + ((size_t)e * II + n0 + srow) * HH + csw;
    const int dofs = tid * 8;                  // 0..2047 elems = 64 rows

    const int qx = (q ^ ((ln >> 1) & 3)) * 8;  // swizzled fragment-read chunk

    f32x4 accg[4][2], accu[4][2];
#pragma unroll
    for (int mi = 0; mi < 4; ++mi)
#pragma unroll
        for (int ni = 0; ni < 2; ++ni) { accg[mi][ni] = (f32x4)0.f; accu[mi][ni] = (f32x4)0.f; }

    // ---- 3-deep counted-vmcnt pipeline over 64 K-tiles ----
    G1_STAGE(0, 0);
    G1_STAGE(1, 32);
    int b0 = 0, b1 = 1, b2 = 2;
    for (int t = 0; t < 62; ++t) {
        G1_STAGE(b2, (t + 2) * 32);            // 12 outstanding / thread max
        VM_WAIT(8);                            // tile t (issued 2 iters ago) landed
        __builtin_amdgcn_s_barrier();          // all threads' tile-t parts landed
        G1_COMPUTE(b0);
        IR_FENCE();
        __builtin_amdgcn_s_barrier();          // all waves done reading buf b0
        const int tb = b0; b0 = b1; b1 = b2; b2 = tb;
    }
    VM_WAIT(4);
    __builtin_amdgcn_s_barrier();
    G1_COMPUTE(b0);                            // tile 62
    VM_WAIT(0);
    __builtin_amdgcn_s_barrier();
    G1_COMPUTE(b1);                            // tile 63

    // epilogue: C/D layout col=lane&15, row=(lane>>4)*4+reg; pad rows have w=0 -> write 0
#pragma unroll
    for (int mi = 0; mi < 4; ++mi) {
#pragma unroll
        for (int r = 0; r < 4; ++r) {
            const int row = wr + mi * 16 + q * 4 + r;
            const float w = wtS[row];
#pragma unroll
            for (int ni = 0; ni < 2; ++ni) {
                const int i = n0 + wc + ni * 16 + ln;
                const float g = accg[mi][ni][r];
                const float u = accu[mi][ni][r];
                const float y = w * u * g / (1.f + __expf(-g));  // w * silu(g) * u
                act_g[(size_t)(off + m0 + row) * II + i] = f2bf(y);
            }
        }
    }
}

// ================= GEMM2 sparse: y_g[row] = act_g[row] @ Wd[e]; plain f32 stores =========
// Tile 64m x 128n; 4 waves side-by-side in n.  Same 3-deep counted-vmcnt pipeline
// (3 loads/stage -> in-loop wait vmcnt(6)).  Grid (e, m=32, n=16): m next-fastest
// after e -> consecutive same-XCD blocks share the Wd B-panel (352KB L2-hot);
// act slab (1.4MB) produced by the SAME XCD in gemm1 -> L2-resident.
#define G2_COMPUTE(B) do { \
    __builtin_amdgcn_s_setprio(1); \
    bf16x8 af[4]; \
    _Pragma("unroll") \
    for (int mi = 0; mi < 4; ++mi) \
        af[mi] = *(const bf16x8*)&As[B][(mi * 16 + ln) * 32 + qx]; \
    _Pragma("unroll") \
    for (int ni = 0; ni < 2; ++ni) { \
        bf16x8 bf = *(const bf16x8*)&Bs[B][(wc2 + ni * 16 + ln) * 32 + qx]; \
        _Pragma("unroll") \
        for (int mi = 0; mi < 4; ++mi) \
            acc[mi][ni] = __builtin_amdgcn_mfma_f32_16x16x32_bf16(af[mi], bf, acc[mi][ni], 0, 0, 0); \
    } \
    __builtin_amdgcn_s_setprio(0); \
} while (0)

#define G2_STAGE(B, KB) do { \
    __builtin_amdgcn_global_load_lds((gas1_t)(pA + (KB)), (las3_t)(&As[B][dofs]), 16, 0, 0); \
    __builtin_amdgcn_global_load_lds((gas1_t)(pB0 + (KB)), (las3_t)(&Bs[B][dofs]), 16, 0, 0); \
    __builtin_amdgcn_global_load_lds((gas1_t)(pB1 + (KB)), (las3_t)(&Bs[B][2048 + dofs]), 16, 0, 0); \
} while (0)

__global__ __launch_bounds__(256, 4)
void k_gemm2s(const u16* __restrict__ act_g,  // [MAXROWS, I] bf16
              const u16* __restrict__ Wdt,    // [E,H,I] bf16
              const int* __restrict__ meta,
              float* __restrict__ y_g) {      // [MAXROWS, H] f32
    const int e = blockIdx.x;
    const int pcnt = meta[8 + e];
    const int m0 = blockIdx.y * 64;
    if (m0 >= pcnt) return;
    const int n0 = blockIdx.z * 128;
    const int off = meta[e];
    const int tid = threadIdx.x;
    const int wave = tid >> 6, lane = tid & 63;
    const int ln = lane & 15, q = lane >> 4;
    const int wc2 = wave * 32;                 // 4 n-cols of waves; all waves share A rows

    __shared__ __align__(16) u16 As[3][64 * 32];
    __shared__ __align__(16) u16 Bs[3][128 * 32];

    // staging: A tile (64x32=4KB): 1 issue; B tile (128x32=8KB): 2 issues.
    const int srow = tid >> 2;                 // 0..63
    const int csw  = (((tid & 3) ^ ((srow >> 1) & 3))) * 8;
    const u16* pA  = act_g + (size_t)(off + m0 + srow) * II + csw;
    const u16* pB0 = Wdt + ((size_t)e * HH + n0 + srow) * II + csw;
    const u16* pB1 = Wdt + ((size_t)e * HH + n0 + srow + 64) * II + csw;
    const int dofs = tid * 8;

    const int qx = (q ^ ((ln >> 1) & 3)) * 8;

    f32x4 acc[4][2];
#pragma unroll
    for (int mi = 0; mi < 4; ++mi)
#pragma unroll
        for (int ni = 0; ni < 2; ++ni) acc[mi][ni] = (f32x4)0.f;

    // ---- 3-deep counted-vmcnt pipeline over 44 K-tiles ----
    G2_STAGE(0, 0);
    G2_STAGE(1, 32);
    int b0 = 0, b1 = 1, b2 = 2;
    for (int t = 0; t < 42; ++t) {
        G2_STAGE(b2, (t + 2) * 32);            // 9 outstanding / thread max
        VM_WAIT(6);                            // tile t landed
        __builtin_amdgcn_s_barrier();
        G2_COMPUTE(b0);
        IR_FENCE();
        __builtin_amdgcn_s_barrier();
        const int tb = b0; b0 = b1; b1 = b2; b2 = tb;
    }
    VM_WAIT(3);
    __builtin_amdgcn_s_barrier();
    G2_COMPUTE(b0);                            // tile 42
    VM_WAIT(0);
    __builtin_amdgcn_s_barrier();
    G2_COMPUTE(b1);                            // tile 43

    // plain stores; padded rows (garbage) never read by k_combine
#pragma unroll
    for (int mi = 0; mi < 4; ++mi) {
#pragma unroll
        for (int r = 0; r < 4; ++r) {
            const int row = mi * 16 + q * 4 + r;
            float* dst = y_g + (size_t)(off + m0 + row) * HH + n0 + wc2;
#pragma unroll
            for (int ni = 0; ni < 2; ++ni)
                dst[ni * 16 + ln] = acc[mi][ni][r];
        }
    }
}

// ---------- combine: out[t] = y_g[slot0(t)] + y_g[slot1(t)] (weights folded in GEMM1) ----
__global__ void k_combine(const float* __restrict__ y_g, const int* __restrict__ slot,
                          const int* __restrict__ meta, const int* __restrict__ flag,
                          void* __restrict__ out) {
    const int gid = blockIdx.x * 256 + threadIdx.x;
    const int t = gid >> 9;                 // 512 threads per token row (H/4)
    const int h = (gid & 511) * 4;
    const int s0 = slot[t * 2 + 0], s1 = slot[t * 2 + 1];
    const int r0 = meta[s0 >> 11] + (s0 & 2047);   // TT == 2048
    const int r1 = meta[s1 >> 11] + (s1 & 2047);
    const float4 a = *(const float4*)&y_g[(size_t)r0 * HH + h];
    const float4 b = *(const float4*)&y_g[(size_t)r1 * HH + h];
    const float4 v = make_float4(a.x + b.x, a.y + b.y, a.z + b.z, a.w + b.w);
    if (flag[0]) {
        *(float4*)((float*)out + (size_t)t * HH + h) = v;
    } else {
        u16* o = (u16*)out + (size_t)t * HH + h;
        o[0] = f2bf(v.x); o[1] = f2bf(v.y); o[2] = f2bf(v.z); o[3] = f2bf(v.w);
    }
}

// ---------- launch ----------
extern "C" void kernel_launch(void* const* d_in, const int* in_sizes, int n_in,
                              void* d_out, int out_size, void* d_ws, size_t ws_size,
                              hipStream_t stream) {
    (void)in_sizes; (void)n_in; (void)out_size;
    const void* hs     = d_in[0];   // [T,H]
    const void* logits = d_in[1];   // [T,E]
    const void* Wg     = d_in[2];   // [E,H,I]
    const void* Wu     = d_in[3];   // [E,H,I]
    const void* Wd     = d_in[4];   // [E,I,H]

    char* ws = (char*)d_ws;
    size_t off = 0;
    int*   flag   = (int*)(ws + off);   off += 256;
    int*   counts = (int*)(ws + off);   off += 256;
    int*   meta   = (int*)(ws + off);   off += 256;
    int*   idx    = (int*)(ws + off);   off += (size_t)EE * TT * 4;       // 64 KB
    float* wt     = (float*)(ws + off); off += (size_t)EE * TT * 4;       // 64 KB
    int*   slot   = (int*)(ws + off);   off += (size_t)TT * 2 * 4;        // 16 KB
    u16*   hs_b   = (u16*)(ws + off);   off += (size_t)TT * HH * 2;       // 8 MB
    u16*   Wgt    = (u16*)(ws + off);   off += (size_t)EE * II * HH * 2;  // 46 MB [E,I,H]
    u16*   Wut    = (u16*)(ws + off);   off += (size_t)EE * II * HH * 2;  // 46 MB [E,I,H]
    u16*   Wdt    = (u16*)(ws + off);   off += (size_t)EE * HH * II * 2;  // 46 MB [E,H,I]
    u16*   act_g  = (u16*)(ws + off);   off += (size_t)MAXROWS * II * 2;  // 14.4 MB
    float* y_g    = (float*)(ws + off); off += (size_t)MAXROWS * HH * 4;  // 42 MB
    if (ws_size < off) return;

    k_sniff<<<dim3(1), dim3(256), 0, stream>>>((const u16*)hs, flag, counts);
    k_routing2<<<dim3(TT / 256), dim3(256), 0, stream>>>(logits, flag, counts, idx, wt, slot);
    k_offsets<<<dim3(1), dim3(64), 0, stream>>>(counts, meta);
    k_cast<<<dim3(TT * HH / (256 * 8)), dim3(256), 0, stream>>>(hs, flag, hs_b);
    // Wg [E,H,I] -> Wgt [E,I,H];  Wu likewise;  Wd [E,I,H] -> Wdt [E,H,I]
    k_transposeP<<<dim3(II / 64, HH / 64, EE), dim3(256), 0, stream>>>(Wg, flag, Wgt, HH, II);
    k_transposeP<<<dim3(II / 64, HH / 64, EE), dim3(256), 0, stream>>>(Wu, flag, Wut, HH, II);
    k_transposeP<<<dim3(HH / 64, II / 64, EE), dim3(256), 0, stream>>>(Wd, flag, Wdt, II, HH);
    // grid (e, m, n): x=e fastest -> expert pinned to XCD; y=m next -> consecutive
    // same-XCD blocks share the (e,n) B-panel in L2 (true m-fastest this time).
    k_gemm1s<<<dim3(EE, TT / 128, II / 64), dim3(256), 0, stream>>>(hs_b, Wgt, Wut, counts, meta, idx, wt, act_g);
    k_gemm2s<<<dim3(EE, TT / 64, HH / 128), dim3(256), 0, stream>>>(act_g, Wdt, meta, y_g);
    k_combine<<<dim3(TT * HH / (256 * 4)), dim3(256), 0, stream>>>(y_g, slot, meta, flag, d_out);
}

// Round 6
// 433.147 us; speedup vs baseline: 1.2986x; 1.2986x over previous
//
#include <hip/hip_runtime.h>
#include <hip/hip_bf16.h>
#include <cstdint>
#include <cstddef>

// Problem constants (HybridMoE): T tokens, H hidden, I intermediate, E experts, top-2.
#define TT 2048
#define HH 2048
#define II 1408
#define EE 8
#define MAXROWS 5120   // sum of 128-padded per-expert counts <= 4096 + 8*127

#define CAST_BLOCKS (TT * HH / (256 * 8))   // 2048
#define TR_BLOCKS   704                     // (II/64)*(HH/64) == (HH/64)*(II/64)

typedef unsigned short u16;
typedef __attribute__((ext_vector_type(8))) __bf16 bf16x8;   // MFMA A/B operand (4 VGPRs)
typedef __attribute__((ext_vector_type(4))) float f32x4;     // MFMA C/D operand

typedef const __attribute__((address_space(1))) uint32_t* gas1_t;
typedef __attribute__((address_space(3))) uint32_t* las3_t;

// counted waitcnt (N = outstanding vector-mem ops allowed to remain)
#define VM_WAIT(N) asm volatile("s_waitcnt vmcnt(" #N ")" ::: "memory")
#define IR_FENCE() asm volatile("" ::: "memory")

// ---------- helpers ----------
__device__ __forceinline__ float bf2f(u16 b) {
    return __uint_as_float(((uint32_t)b) << 16);
}
__device__ __forceinline__ u16 f2bf(float x) {   // round-to-nearest-even
    uint32_t u = __float_as_uint(x);
    u += 0x7fffu + ((u >> 16) & 1u);
    return (u16)(u >> 16);
}

// ---------- fused routing: sniff + top-2 softmax + offsets, ONE single-block launch ----
__global__ void k_route(const u16* __restrict__ hs_raw, const void* __restrict__ logits,
                        int* __restrict__ flag_g, int* __restrict__ counts_g,
                        int* __restrict__ meta, int* __restrict__ idx,
                        float* __restrict__ wt, int* __restrict__ slot) {
    __shared__ int cnt;
    __shared__ int cS[EE];
    __shared__ int flagS;
    const int tid = threadIdx.x;
    if (tid < EE) cS[tid] = 0;
    if (tid == 0) cnt = 0;
    __syncthreads();
    // dtype sniff over first 4096 raw u16 of hidden_states
    int w = 0;
    for (int i = tid; i < 4096; i += 1024) {
        u16 x = hs_raw[i];
        if (x & 0x7fff) {
            int ex = (x >> 7) & 0xff;
            if (ex == 0xff || ex < 100 || ex > 140) ++w;
        }
    }
    atomicAdd(&cnt, w);
    __syncthreads();
    if (tid == 0) { flagS = (cnt > 100) ? 1 : 0; flag_g[0] = flagS; }
    __syncthreads();
    const int f = flagS;
    // top-2 routing, 2 tokens per thread, LDS-atomic per-expert counters
    for (int t = tid; t < TT; t += 1024) {
        float v[EE];
#pragma unroll
        for (int e = 0; e < EE; ++e)
            v[e] = f ? ((const float*)logits)[t * EE + e]
                     : bf2f(((const u16*)logits)[t * EE + e]);
        int i0 = 0; float v0 = v[0];
#pragma unroll
        for (int e = 1; e < EE; ++e) { if (v[e] > v0) { v0 = v[e]; i0 = e; } }
        int i1 = -1; float v1 = -3.4e38f;
#pragma unroll
        for (int e = 0; e < EE; ++e) { if (e != i0 && v[e] > v1) { v1 = v[e]; i1 = e; } }
        float r = __expf(v1 - v0);          // <= 1
        float s = 1.f / (1.f + r);
        int p0 = atomicAdd(&cS[i0], 1);
        idx[i0 * TT + p0] = t; wt[i0 * TT + p0] = s;
        slot[t * 2 + 0] = i0 * TT + p0;
        int p1 = atomicAdd(&cS[i1], 1);
        idx[i1 * TT + p1] = t; wt[i1 * TT + p1] = r * s;
        slot[t * 2 + 1] = i1 * TT + p1;
    }
    __syncthreads();
    if (tid == 0) {
        int off = 0;
        for (int e = 0; e < EE; ++e) {
            int c = cS[e];
            counts_g[e] = c;
            int p = (c + 127) & ~127;
            meta[e] = off; meta[8 + e] = p;
            off += p;
        }
    }
}

// ---------- packed 64x64 transpose tile body: src[R,C] (f32/bf16) -> dst[C,R] bf16 ----
// Row-pairs packed into u32, write b32 / read b64: <=4-way LDS aliasing (old scalar
// u16 version was 8-way).  Validated round-5.
__device__ __forceinline__ void transpose_tile(const void* __restrict__ src,
                                               u16* __restrict__ dst,
                                               uint32_t* TTs, int R, int C,
                                               int r0, int c0, int f, int tid) {
    const int cg = (tid & 15) * 4;       // col group (4 cols)
    const int rh = tid >> 4;             // 0..15
#pragma unroll
    for (int p = 0; p < 2; ++p) {
        const int rp = rh + 16 * p;      // row-pair index 0..31
        const int r  = 2 * rp;
        const size_t base = (size_t)(r0 + r) * C + c0 + cg;
        uint32_t w0, w1, w2, w3;
        if (f) {
            const float4 v0 = *(const float4*)((const float*)src + base);
            const float4 v1 = *(const float4*)((const float*)src + base + C);
            w0 = (uint32_t)f2bf(v0.x) | ((uint32_t)f2bf(v1.x) << 16);
            w1 = (uint32_t)f2bf(v0.y) | ((uint32_t)f2bf(v1.y) << 16);
            w2 = (uint32_t)f2bf(v0.z) | ((uint32_t)f2bf(v1.z) << 16);
            w3 = (uint32_t)f2bf(v0.w) | ((uint32_t)f2bf(v1.w) << 16);
        } else {
            const ushort4 v0 = *(const ushort4*)((const u16*)src + base);
            const ushort4 v1 = *(const ushort4*)((const u16*)src + base + C);
            w0 = (uint32_t)v0.x | ((uint32_t)v1.x << 16);
            w1 = (uint32_t)v0.y | ((uint32_t)v1.y << 16);
            w2 = (uint32_t)v0.z | ((uint32_t)v1.z << 16);
            w3 = (uint32_t)v0.w | ((uint32_t)v1.w << 16);
        }
        TTs[(cg + 0) * 34 + rp] = w0;
        TTs[(cg + 1) * 34 + rp] = w1;
        TTs[(cg + 2) * 34 + rp] = w2;
        TTs[(cg + 3) * 34 + rp] = w3;
    }
    __syncthreads();
    const int c = tid >> 2, u = tid & 3;
    uint32_t o[8];
#pragma unroll
    for (int k = 0; k < 4; ++k) {
        const int rp = 8 * u + 2 * k;
        o[2 * k]     = TTs[c * 34 + rp];
        o[2 * k + 1] = TTs[c * 34 + rp + 1];
    }
    u16* dp = dst + (size_t)(c0 + c) * R + r0 + 16 * u;
    *(uint4*)(dp)     = make_uint4(o[0], o[1], o[2], o[3]);
    *(uint4*)(dp + 8) = make_uint4(o[4], o[5], o[6], o[7]);
}

// ---------- fused preprocessing: hs cast + Wg/Wu/Wd transposes, ONE launch ----------
// Flat grid: [0,2048) = cast slices; then 24 groups of 704 transpose tiles
// (8 experts x Wg, 8 x Wu, 8 x Wd).
__global__ void k_prep(const void* __restrict__ hs, const void* __restrict__ Wg,
                       const void* __restrict__ Wu, const void* __restrict__ Wd,
                       const int* __restrict__ flag,
                       u16* __restrict__ hs_b, u16* __restrict__ Wgt,
                       u16* __restrict__ Wut, u16* __restrict__ Wdt) {
    __shared__ uint32_t TTs[64 * 34];
    const int bid = blockIdx.x;
    const int tid = threadIdx.x;
    const int f = flag[0];
    if (bid < CAST_BLOCKS) {
        const int i0 = (bid * 256 + tid) * 8;
        if (f) {
            const float* s = (const float*)hs;
#pragma unroll
            for (int j = 0; j < 8; ++j) hs_b[i0 + j] = f2bf(s[i0 + j]);
        } else {
            const u16* s = (const u16*)hs;
            *(uint4*)&hs_b[i0] = *(const uint4*)&s[i0];
        }
        return;
    }
    const int rr = bid - CAST_BLOCKS;
    const int z = rr / TR_BLOCKS;        // 0..23
    const int b = rr - z * TR_BLOCKS;    // 0..703
    const size_t eo = (size_t)(z & 7) * (size_t)HH * (size_t)II;  // same product all mats
    if (z < 16) {
        // Wg/Wu: src [HH, II] -> dst [II, HH]; tile grid 22 x 32
        const int cx = b % 22, cy = b / 22;
        const void* srcp;
        u16* dstp;
        if (z < 8) { srcp = f ? (const void*)((const float*)Wg + eo) : (const void*)((const u16*)Wg + eo);
                     dstp = Wgt + eo; }
        else       { srcp = f ? (const void*)((const float*)Wu + eo) : (const void*)((const u16*)Wu + eo);
                     dstp = Wut + eo; }
        transpose_tile(srcp, dstp, TTs, HH, II, cy * 64, cx * 64, f, tid);
    } else {
        // Wd: src [II, HH] -> dst [HH, II]; tile grid 32 x 22
        const int cx = b % 32, cy = b / 32;
        const void* srcp = f ? (const void*)((const float*)Wd + eo) : (const void*)((const u16*)Wd + eo);
        transpose_tile(srcp, Wdt + eo, TTs, II, HH, cy * 64, cx * 64, f, tid);
    }
}

// ================= GEMM1 sparse (dual), 512 threads / 8 waves (round-3 best) ==========
// 2-buffer counted-vmcnt pipeline: stage(t+1); vmcnt(3); barrier; compute(t); barrier.
// Grid (e=8, n=11, m=16): x=e fastest -> expert pinned to XCD; y=n next -> same-XCD
// blocks share the A m-slab / stream B panels (empirically best: 80.5us, FETCH 53MB).
// XOR bank swizzle (round-1: conflicts 6.5e6 -> 0).

#define G1_COMPUTE(B) do { \
    __builtin_amdgcn_s_setprio(1); \
    bf16x8 af[4]; \
    _Pragma("unroll") \
    for (int mi = 0; mi < 4; ++mi) \
        af[mi] = *(const bf16x8*)&As[B][(wr + mi * 16 + ln) * 32 + qx]; \
    _Pragma("unroll") \
    for (int ni = 0; ni < 2; ++ni) { \
        bf16x8 bgf = *(const bf16x8*)&Bg[B][(wc + ni * 16 + ln) * 32 + qx]; \
        bf16x8 buf_ = *(const bf16x8*)&Bu[B][(wc + ni * 16 + ln) * 32 + qx]; \
        _Pragma("unroll") \
        for (int mi = 0; mi < 4; ++mi) { \
            accg[mi][ni] = __builtin_amdgcn_mfma_f32_16x16x32_bf16(af[mi], bgf, accg[mi][ni], 0, 0, 0); \
            accu[mi][ni] = __builtin_amdgcn_mfma_f32_16x16x32_bf16(af[mi], buf_, accu[mi][ni], 0, 0, 0); \
        } \
    } \
    __builtin_amdgcn_s_setprio(0); \
} while (0)

#define G1_STAGE(B, KB) do { \
    __builtin_amdgcn_global_load_lds((gas1_t)(pA + (KB)), (las3_t)(&As[B][dofs]), 16, 0, 0); \
    __builtin_amdgcn_global_load_lds((gas1_t)(pG + (KB)), (las3_t)(&Bg[B][dofs]), 16, 0, 0); \
    __builtin_amdgcn_global_load_lds((gas1_t)(pU + (KB)), (las3_t)(&Bu[B][dofs]), 16, 0, 0); \
} while (0)

__global__ __launch_bounds__(512, 4)
void k_gemm1s(const u16* __restrict__ hs_b,  // [T,H] bf16
              const u16* __restrict__ Wgt,   // [E,I,H] bf16
              const u16* __restrict__ Wut,   // [E,I,H] bf16
              const int* __restrict__ counts,
              const int* __restrict__ meta,
              const int* __restrict__ idx,
              const float* __restrict__ wt,
              u16* __restrict__ act_g) {     // [MAXROWS, I] bf16
    const int e = blockIdx.x;
    const int cnt = counts[e];
    const int pcnt = meta[8 + e];
    const int m0 = blockIdx.z * 128;
    if (m0 >= pcnt) return;
    const int n0 = blockIdx.y * 128;
    const int off = meta[e];
    const int tid = threadIdx.x;
    const int wave = tid >> 6, lane = tid & 63;
    const int ln = lane & 15, q = lane >> 4;
    const int wr = (wave >> 2) * 64;           // 2 m-rows of waves
    const int wc = (wave & 3) * 32;            // 4 n-cols of waves

    __shared__ __align__(16) u16 As[2][128 * 32];
    __shared__ __align__(16) u16 Bg[2][128 * 32];
    __shared__ __align__(16) u16 Bu[2][128 * 32];
    __shared__ int   tokS[128];
    __shared__ float wtS[128];

    if (tid < 128) {
        const int pos = m0 + tid;
        const bool v = pos < cnt;
        tokS[tid] = v ? idx[e * TT + pos] : 0;
        wtS[tid]  = v ? wt[e * TT + pos] : 0.f;
    }
    __syncthreads();   // tokS visible; vmcnt drained -> pipeline starts at 0 outstanding

    // staging geometry: 512 threads x 16B = one 128x32 tile per issue; LDS dest linear,
    // source column XOR-swizzled so read chunk q^((row>>1)&3) returns global chunk q.
    const int srow = tid >> 2;                 // 0..127
    const int csw  = (((tid & 3) ^ ((srow >> 1) & 3))) * 8;
    const u16* pA = hs_b + (size_t)tokS[srow] * HH + csw;        // gathered token row
    const u16* pG = Wgt + ((size_t)e * II + n0 + srow) * HH + csw;
    const u16* pU = Wut + ((size_t)e * II + n0 + srow) * HH + csw;
    const int dofs = tid * 8;                  // == srow*32 + (tid&3)*8

    const int qx = (q ^ ((ln >> 1) & 3)) * 8;  // swizzled fragment-read chunk

    f32x4 accg[4][2], accu[4][2];
#pragma unroll
    for (int mi = 0; mi < 4; ++mi)
#pragma unroll
        for (int ni = 0; ni < 2; ++ni) { accg[mi][ni] = (f32x4)0.f; accu[mi][ni] = (f32x4)0.f; }

    // ---- 2-buffer counted-vmcnt pipeline over 64 K-tiles ----
    G1_STAGE(0, 0);
    int cur = 0;
    for (int t = 0; t < 63; ++t) {
        G1_STAGE(cur ^ 1, (t + 1) * 32);       // 6 outstanding / wave
        VM_WAIT(3);                            // tile t (issued last iter) landed
        __builtin_amdgcn_s_barrier();          // all waves' tile-t parts landed
        G1_COMPUTE(cur);
        IR_FENCE();
        __builtin_amdgcn_s_barrier();          // all waves done reading buf cur
        cur ^= 1;
    }
    VM_WAIT(0);
    __builtin_amdgcn_s_barrier();
    G1_COMPUTE(cur);                           // tile 63

    // epilogue: C/D layout col=lane&15, row=(lane>>4)*4+reg; pad rows have w=0 -> write 0
#pragma unroll
    for (int mi = 0; mi < 4; ++mi) {
#pragma unroll
        for (int r = 0; r < 4; ++r) {
            const int row = wr + mi * 16 + q * 4 + r;
            const float w = wtS[row];
#pragma unroll
            for (int ni = 0; ni < 2; ++ni) {
                const int i = n0 + wc + ni * 16 + ln;
                const float g = accg[mi][ni][r];
                const float u = accu[mi][ni][r];
                const float y = w * u * g / (1.f + __expf(-g));  // w * silu(g) * u
                act_g[(size_t)(off + m0 + row) * II + i] = f2bf(y);
            }
        }
    }
}

// ================= GEMM2 sparse (round-3 best): y_g[row] = act_g[row] @ Wd[e] =========
// 256 threads, tile 128x128, 2-buffer counted-vmcnt (4 loads/stage -> vmcnt(4)).
#define G2_COMPUTE(B) do { \
    __builtin_amdgcn_s_setprio(1); \
    bf16x8 af[4]; \
    _Pragma("unroll") \
    for (int mi = 0; mi < 4; ++mi) \
        af[mi] = *(const bf16x8*)&As[B][(wr + mi * 16 + ln) * 32 + qx]; \
    _Pragma("unroll") \
    for (int ni = 0; ni < 4; ++ni) { \
        bf16x8 bf = *(const bf16x8*)&Bs[B][(wc + ni * 16 + ln) * 32 + qx]; \
        _Pragma("unroll") \
        for (int mi = 0; mi < 4; ++mi) \
            acc[mi][ni] = __builtin_amdgcn_mfma_f32_16x16x32_bf16(af[mi], bf, acc[mi][ni], 0, 0, 0); \
    } \
    __builtin_amdgcn_s_setprio(0); \
} while (0)

#define G2_STAGE(B, KB) do { \
    __builtin_amdgcn_global_load_lds((gas1_t)(pA0 + (KB)), (las3_t)(&As[B][dofs]), 16, 0, 0); \
    __builtin_amdgcn_global_load_lds((gas1_t)(pA1 + (KB)), (las3_t)(&As[B][2048 + dofs]), 16, 0, 0); \
    __builtin_amdgcn_global_load_lds((gas1_t)(pB0 + (KB)), (las3_t)(&Bs[B][dofs]), 16, 0, 0); \
    __builtin_amdgcn_global_load_lds((gas1_t)(pB1 + (KB)), (las3_t)(&Bs[B][2048 + dofs]), 16, 0, 0); \
} while (0)

__global__ __launch_bounds__(256, 4)
void k_gemm2s(const u16* __restrict__ act_g,  // [MAXROWS, I] bf16
              const u16* __restrict__ Wdt,    // [E,H,I] bf16
              const int* __restrict__ meta,
              float* __restrict__ y_g) {      // [MAXROWS, H] f32
    const int e = blockIdx.x;
    const int pcnt = meta[8 + e];
    const int m0 = blockIdx.z * 128;
    if (m0 >= pcnt) return;
    const int n0 = blockIdx.y * 128;
    const int off = meta[e];
    const int tid = threadIdx.x;
    const int wave = tid >> 6, lane = tid & 63;
    const int ln = lane & 15, q = lane >> 4;
    const int wr = (wave >> 1) * 64, wc = (wave & 1) * 64;

    __shared__ __align__(16) u16 As[2][128 * 32];
    __shared__ __align__(16) u16 Bs[2][128 * 32];

    // staging: 256 threads x 16B = half tile per issue; 2 issues per tile.
    const int srow = tid >> 2;                 // 0..63 (+64 for second half; swizzle identical)
    const int csw  = (((tid & 3) ^ ((srow >> 1) & 3))) * 8;
    const u16* bA = act_g + (size_t)(off + m0) * II;
    const u16* bB = Wdt + ((size_t)e * HH + n0) * II;
    const u16* pA0 = bA + (size_t)srow * II + csw;
    const u16* pA1 = bA + (size_t)(srow + 64) * II + csw;
    const u16* pB0 = bB + (size_t)srow * II + csw;
    const u16* pB1 = bB + (size_t)(srow + 64) * II + csw;
    const int dofs = tid * 8;

    const int qx = (q ^ ((ln >> 1) & 3)) * 8;

    f32x4 acc[4][4];
#pragma unroll
    for (int mi = 0; mi < 4; ++mi)
#pragma unroll
        for (int ni = 0; ni < 4; ++ni) acc[mi][ni] = (f32x4)0.f;

    // ---- 2-buffer counted-vmcnt pipeline over 44 K-tiles ----
    G2_STAGE(0, 0);
    int cur = 0;
    for (int t = 0; t < 43; ++t) {
        G2_STAGE(cur ^ 1, (t + 1) * 32);       // 8 outstanding / wave
        VM_WAIT(4);                            // tile t landed
        __builtin_amdgcn_s_barrier();
        G2_COMPUTE(cur);
        IR_FENCE();
        __builtin_amdgcn_s_barrier();
        cur ^= 1;
    }
    VM_WAIT(0);
    __builtin_amdgcn_s_barrier();
    G2_COMPUTE(cur);                           // tile 43

    // plain stores; padded rows (garbage) never read by k_combine
#pragma unroll
    for (int mi = 0; mi < 4; ++mi) {
#pragma unroll
        for (int r = 0; r < 4; ++r) {
            const int row = wr + mi * 16 + q * 4 + r;
            float* dst = y_g + (size_t)(off + m0 + row) * HH + n0 + wc;
#pragma unroll
            for (int ni = 0; ni < 4; ++ni)
                dst[ni * 16 + ln] = acc[mi][ni][r];
        }
    }
}

// ---------- combine: out[t] = y_g[slot0(t)] + y_g[slot1(t)] (weights folded in GEMM1) ----
__global__ void k_combine(const float* __restrict__ y_g, const int* __restrict__ slot,
                          const int* __restrict__ meta, const int* __restrict__ flag,
                          void* __restrict__ out) {
    const int gid = blockIdx.x * 256 + threadIdx.x;
    const int t = gid >> 9;                 // 512 threads per token row (H/4)
    const int h = (gid & 511) * 4;
    const int s0 = slot[t * 2 + 0], s1 = slot[t * 2 + 1];
    const int r0 = meta[s0 >> 11] + (s0 & 2047);   // TT == 2048
    const int r1 = meta[s1 >> 11] + (s1 & 2047);
    const float4 a = *(const float4*)&y_g[(size_t)r0 * HH + h];
    const float4 b = *(const float4*)&y_g[(size_t)r1 * HH + h];
    const float4 v = make_float4(a.x + b.x, a.y + b.y, a.z + b.z, a.w + b.w);
    if (flag[0]) {
        *(float4*)((float*)out + (size_t)t * HH + h) = v;
    } else {
        u16* o = (u16*)out + (size_t)t * HH + h;
        o[0] = f2bf(v.x); o[1] = f2bf(v.y); o[2] = f2bf(v.z); o[3] = f2bf(v.w);
    }
}

// ---------- launch ----------
extern "C" void kernel_launch(void* const* d_in, const int* in_sizes, int n_in,
                              void* d_out, int out_size, void* d_ws, size_t ws_size,
                              hipStream_t stream) {
    (void)in_sizes; (void)n_in; (void)out_size;
    const void* hs     = d_in[0];   // [T,H]
    const void* logits = d_in[1];   // [T,E]
    const void* Wg     = d_in[2];   // [E,H,I]
    const void* Wu     = d_in[3];   // [E,H,I]
    const void* Wd     = d_in[4];   // [E,I,H]

    char* ws = (char*)d_ws;
    size_t off = 0;
    int*   flag   = (int*)(ws + off);   off += 256;
    int*   counts = (int*)(ws + off);   off += 256;
    int*   meta   = (int*)(ws + off);   off += 256;
    int*   idx    = (int*)(ws + off);   off += (size_t)EE * TT * 4;       // 64 KB
    float* wt     = (float*)(ws + off); off += (size_t)EE * TT * 4;       // 64 KB
    int*   slot   = (int*)(ws + off);   off += (size_t)TT * 2 * 4;        // 16 KB
    u16*   hs_b   = (u16*)(ws + off);   off += (size_t)TT * HH * 2;       // 8 MB
    u16*   Wgt    = (u16*)(ws + off);   off += (size_t)EE * II * HH * 2;  // 46 MB [E,I,H]
    u16*   Wut    = (u16*)(ws + off);   off += (size_t)EE * II * HH * 2;  // 46 MB [E,I,H]
    u16*   Wdt    = (u16*)(ws + off);   off += (size_t)EE * HH * II * 2;  // 46 MB [E,H,I]
    u16*   act_g  = (u16*)(ws + off);   off += (size_t)MAXROWS * II * 2;  // 14.4 MB
    float* y_g    = (float*)(ws + off); off += (size_t)MAXROWS * HH * 4;  // 42 MB
    if (ws_size < off) return;

    // 5 launches total (was 10): route, prep, gemm1, gemm2, combine
    k_route<<<dim3(1), dim3(1024), 0, stream>>>((const u16*)hs, logits, flag, counts,
                                                meta, idx, wt, slot);
    k_prep<<<dim3(CAST_BLOCKS + 24 * TR_BLOCKS), dim3(256), 0, stream>>>(
        hs, Wg, Wu, Wd, flag, hs_b, Wgt, Wut, Wdt);
    k_gemm1s<<<dim3(EE, II / 128, TT / 128), dim3(512), 0, stream>>>(hs_b, Wgt, Wut,
                                                counts, meta, idx, wt, act_g);
    k_gemm2s<<<dim3(EE, HH / 128, TT / 128), dim3(256), 0, stream>>>(act_g, Wdt, meta, y_g);
    k_combine<<<dim3(TT * HH / (256 * 4)), dim3(256), 0, stream>>>(y_g, slot, meta, flag, d_out);
}

// Round 7
// 432.863 us; speedup vs baseline: 1.2994x; 1.0007x over previous
//
#include <hip/hip_runtime.h>
#include <hip/hip_bf16.h>
#include <cstdint>
#include <cstddef>

// Problem constants (HybridMoE): T tokens, H hidden, I intermediate, E experts, top-2.
#define TT 2048
#define HH 2048
#define II 1408
#define EE 8
#define MAXROWS 5120   // sum of 128-padded per-expert counts <= 4096 + 8*127

#define CAST_BLOCKS (TT * HH / (256 * 8))   // 2048
#define TR_BLOCKS   704                     // (II/64)*(HH/64) == (HH/64)*(II/64)

typedef unsigned short u16;
typedef __attribute__((ext_vector_type(8))) __bf16 bf16x8;   // MFMA A/B operand (4 VGPRs)
typedef __attribute__((ext_vector_type(4))) float f32x4;     // MFMA C/D operand

typedef const __attribute__((address_space(1))) uint32_t* gas1_t;
typedef __attribute__((address_space(3))) uint32_t* las3_t;

// counted waitcnt (N = outstanding vector-mem ops allowed to remain)
#define VM_WAIT(N) asm volatile("s_waitcnt vmcnt(" #N ")" ::: "memory")
#define IR_FENCE() asm volatile("" ::: "memory")

// ---------- helpers ----------
__device__ __forceinline__ float bf2f(u16 b) {
    return __uint_as_float(((uint32_t)b) << 16);
}
__device__ __forceinline__ u16 f2bf(float x) {   // round-to-nearest-even
    uint32_t u = __float_as_uint(x);
    u += 0x7fffu + ((u >> 16) & 1u);
    return (u16)(u >> 16);
}
__device__ __forceinline__ uint32_t pack2bf(float lo, float hi) {
    return (uint32_t)f2bf(lo) | ((uint32_t)f2bf(hi) << 16);
}

// ---------- fused routing: sniff + top-2 softmax + offsets, ONE single-block launch ----
__global__ void k_route(const u16* __restrict__ hs_raw, const void* __restrict__ logits,
                        int* __restrict__ flag_g, int* __restrict__ counts_g,
                        int* __restrict__ meta, int* __restrict__ idx,
                        float* __restrict__ wt, int* __restrict__ slot) {
    __shared__ int cnt;
    __shared__ int cS[EE];
    __shared__ int flagS;
    const int tid = threadIdx.x;
    if (tid < EE) cS[tid] = 0;
    if (tid == 0) cnt = 0;
    __syncthreads();
    // dtype sniff over first 4096 raw u16 of hidden_states
    int w = 0;
    for (int i = tid; i < 4096; i += 1024) {
        u16 x = hs_raw[i];
        if (x & 0x7fff) {
            int ex = (x >> 7) & 0xff;
            if (ex == 0xff || ex < 100 || ex > 140) ++w;
        }
    }
    atomicAdd(&cnt, w);
    __syncthreads();
    if (tid == 0) { flagS = (cnt > 100) ? 1 : 0; flag_g[0] = flagS; }
    __syncthreads();
    const int f = flagS;
    // top-2 routing, 2 tokens per thread, LDS-atomic per-expert counters
    for (int t = tid; t < TT; t += 1024) {
        float v[EE];
#pragma unroll
        for (int e = 0; e < EE; ++e)
            v[e] = f ? ((const float*)logits)[t * EE + e]
                     : bf2f(((const u16*)logits)[t * EE + e]);
        int i0 = 0; float v0 = v[0];
#pragma unroll
        for (int e = 1; e < EE; ++e) { if (v[e] > v0) { v0 = v[e]; i0 = e; } }
        int i1 = -1; float v1 = -3.4e38f;
#pragma unroll
        for (int e = 0; e < EE; ++e) { if (e != i0 && v[e] > v1) { v1 = v[e]; i1 = e; } }
        float r = __expf(v1 - v0);          // <= 1
        float s = 1.f / (1.f + r);
        int p0 = atomicAdd(&cS[i0], 1);
        idx[i0 * TT + p0] = t; wt[i0 * TT + p0] = s;
        slot[t * 2 + 0] = i0 * TT + p0;
        int p1 = atomicAdd(&cS[i1], 1);
        idx[i1 * TT + p1] = t; wt[i1 * TT + p1] = r * s;
        slot[t * 2 + 1] = i1 * TT + p1;
    }
    __syncthreads();
    if (tid == 0) {
        int off = 0;
        for (int e = 0; e < EE; ++e) {
            int c = cS[e];
            counts_g[e] = c;
            int p = (c + 127) & ~127;
            meta[e] = off; meta[8 + e] = p;
            off += p;
        }
    }
}

// ---------- packed 64x64 transpose tile body: src[R,C] (f32/bf16) -> dst[C,R] bf16 ----
// Row-pairs packed into u32, write b32 / read b64.  LDS stride 33 (odd):
// write bank = (4c'+j+rp)%32 and read bank = (c+8u+2k)%32 are both <=2-way
// (2-way is free, m136); the old stride 34 was 4-way on both sides
// (3.2M SQ_LDS_BANK_CONFLICT/dispatch, round-6 PMC).
__device__ __forceinline__ void transpose_tile(const void* __restrict__ src,
                                               u16* __restrict__ dst,
                                               uint32_t* TTs, int R, int C,
                                               int r0, int c0, int f, int tid) {
    const int cg = (tid & 15) * 4;       // col group (4 cols)
    const int rh = tid >> 4;             // 0..15
#pragma unroll
    for (int p = 0; p < 2; ++p) {
        const int rp = rh + 16 * p;      // row-pair index 0..31
        const int r  = 2 * rp;
        const size_t base = (size_t)(r0 + r) * C + c0 + cg;
        uint32_t w0, w1, w2, w3;
        if (f) {
            const float4 v0 = *(const float4*)((const float*)src + base);
            const float4 v1 = *(const float4*)((const float*)src + base + C);
            w0 = pack2bf(v0.x, v1.x);
            w1 = pack2bf(v0.y, v1.y);
            w2 = pack2bf(v0.z, v1.z);
            w3 = pack2bf(v0.w, v1.w);
        } else {
            const ushort4 v0 = *(const ushort4*)((const u16*)src + base);
            const ushort4 v1 = *(const ushort4*)((const u16*)src + base + C);
            w0 = (uint32_t)v0.x | ((uint32_t)v1.x << 16);
            w1 = (uint32_t)v0.y | ((uint32_t)v1.y << 16);
            w2 = (uint32_t)v0.z | ((uint32_t)v1.z << 16);
            w3 = (uint32_t)v0.w | ((uint32_t)v1.w << 16);
        }
        TTs[(cg + 0) * 33 + rp] = w0;
        TTs[(cg + 1) * 33 + rp] = w1;
        TTs[(cg + 2) * 33 + rp] = w2;
        TTs[(cg + 3) * 33 + rp] = w3;
    }
    __syncthreads();
    const int c = tid >> 2, u = tid & 3;
    uint32_t o[8];
#pragma unroll
    for (int k = 0; k < 4; ++k) {
        const int rp = 8 * u + 2 * k;
        o[2 * k]     = TTs[c * 33 + rp];
        o[2 * k + 1] = TTs[c * 33 + rp + 1];
    }
    u16* dp = dst + (size_t)(c0 + c) * R + r0 + 16 * u;
    *(uint4*)(dp)     = make_uint4(o[0], o[1], o[2], o[3]);
    *(uint4*)(dp + 8) = make_uint4(o[4], o[5], o[6], o[7]);
}

// ---------- fused preprocessing: hs cast + Wg/Wu/Wd transposes, ONE launch ----------
// Flat grid: [0,2048) = cast slices; then 24 groups of 704 transpose tiles
// (8 experts x Wg, 8 x Wu, 8 x Wd).  Cast path vectorized (G13): 2x float4 read,
// packed uint4 store (round-6 version did 8 scalar dword loads + 8 scalar 2B
// stores -> 8x write amplification).
__global__ void k_prep(const void* __restrict__ hs, const void* __restrict__ Wg,
                       const void* __restrict__ Wu, const void* __restrict__ Wd,
                       const int* __restrict__ flag,
                       u16* __restrict__ hs_b, u16* __restrict__ Wgt,
                       u16* __restrict__ Wut, u16* __restrict__ Wdt) {
    __shared__ uint32_t TTs[64 * 33];
    const int bid = blockIdx.x;
    const int tid = threadIdx.x;
    const int f = flag[0];
    if (bid < CAST_BLOCKS) {
        const int i0 = (bid * 256 + tid) * 8;
        if (f) {
            const float4 v0 = *(const float4*)((const float*)hs + i0);
            const float4 v1 = *(const float4*)((const float*)hs + i0 + 4);
            *(uint4*)&hs_b[i0] = make_uint4(pack2bf(v0.x, v0.y), pack2bf(v0.z, v0.w),
                                            pack2bf(v1.x, v1.y), pack2bf(v1.z, v1.w));
        } else {
            *(uint4*)&hs_b[i0] = *(const uint4*)((const u16*)hs + i0);
        }
        return;
    }
    const int rr = bid - CAST_BLOCKS;
    const int z = rr / TR_BLOCKS;        // 0..23
    const int b = rr - z * TR_BLOCKS;    // 0..703
    const size_t eo = (size_t)(z & 7) * (size_t)HH * (size_t)II;  // same product all mats
    if (z < 16) {
        // Wg/Wu: src [HH, II] -> dst [II, HH]; tile grid 22 x 32
        const int cx = b % 22, cy = b / 22;
        const void* srcp;
        u16* dstp;
        if (z < 8) { srcp = f ? (const void*)((const float*)Wg + eo) : (const void*)((const u16*)Wg + eo);
                     dstp = Wgt + eo; }
        else       { srcp = f ? (const void*)((const float*)Wu + eo) : (const void*)((const u16*)Wu + eo);
                     dstp = Wut + eo; }
        transpose_tile(srcp, dstp, TTs, HH, II, cy * 64, cx * 64, f, tid);
    } else {
        // Wd: src [II, HH] -> dst [HH, II]; tile grid 32 x 22
        const int cx = b % 32, cy = b / 32;
        const void* srcp = f ? (const void*)((const float*)Wd + eo) : (const void*)((const u16*)Wd + eo);
        transpose_tile(srcp, Wdt + eo, TTs, II, HH, cy * 64, cx * 64, f, tid);
    }
}

// ================= GEMM1 sparse (dual), 512 threads / 8 waves (round-3 best) ==========
// 2-buffer counted-vmcnt pipeline: stage(t+1); vmcnt(3); barrier; compute(t); barrier.
// Grid (e=8, n=11, m=16): x=e fastest -> expert pinned to XCD; y=n next -> same-XCD
// blocks share the A m-slab / stream B panels (empirically best: 80.5us, FETCH 53MB).
// XOR bank swizzle (round-1: conflicts 6.5e6 -> 0).

#define G1_COMPUTE(B) do { \
    __builtin_amdgcn_s_setprio(1); \
    bf16x8 af[4]; \
    _Pragma("unroll") \
    for (int mi = 0; mi < 4; ++mi) \
        af[mi] = *(const bf16x8*)&As[B][(wr + mi * 16 + ln) * 32 + qx]; \
    _Pragma("unroll") \
    for (int ni = 0; ni < 2; ++ni) { \
        bf16x8 bgf = *(const bf16x8*)&Bg[B][(wc + ni * 16 + ln) * 32 + qx]; \
        bf16x8 buf_ = *(const bf16x8*)&Bu[B][(wc + ni * 16 + ln) * 32 + qx]; \
        _Pragma("unroll") \
        for (int mi = 0; mi < 4; ++mi) { \
            accg[mi][ni] = __builtin_amdgcn_mfma_f32_16x16x32_bf16(af[mi], bgf, accg[mi][ni], 0, 0, 0); \
            accu[mi][ni] = __builtin_amdgcn_mfma_f32_16x16x32_bf16(af[mi], buf_, accu[mi][ni], 0, 0, 0); \
        } \
    } \
    __builtin_amdgcn_s_setprio(0); \
} while (0)

#define G1_STAGE(B, KB) do { \
    __builtin_amdgcn_global_load_lds((gas1_t)(pA + (KB)), (las3_t)(&As[B][dofs]), 16, 0, 0); \
    __builtin_amdgcn_global_load_lds((gas1_t)(pG + (KB)), (las3_t)(&Bg[B][dofs]), 16, 0, 0); \
    __builtin_amdgcn_global_load_lds((gas1_t)(pU + (KB)), (las3_t)(&Bu[B][dofs]), 16, 0, 0); \
} while (0)

__global__ __launch_bounds__(512, 4)
void k_gemm1s(const u16* __restrict__ hs_b,  // [T,H] bf16
              const u16* __restrict__ Wgt,   // [E,I,H] bf16
              const u16* __restrict__ Wut,   // [E,I,H] bf16
              const int* __restrict__ counts,
              const int* __restrict__ meta,
              const int* __restrict__ idx,
              const float* __restrict__ wt,
              u16* __restrict__ act_g) {     // [MAXROWS, I] bf16
    const int e = blockIdx.x;
    const int cnt = counts[e];
    const int pcnt = meta[8 + e];
    const int m0 = blockIdx.z * 128;
    if (m0 >= pcnt) return;
    const int n0 = blockIdx.y * 128;
    const int off = meta[e];
    const int tid = threadIdx.x;
    const int wave = tid >> 6, lane = tid & 63;
    const int ln = lane & 15, q = lane >> 4;
    const int wr = (wave >> 2) * 64;           // 2 m-rows of waves
    const int wc = (wave & 3) * 32;            // 4 n-cols of waves

    __shared__ __align__(16) u16 As[2][128 * 32];
    __shared__ __align__(16) u16 Bg[2][128 * 32];
    __shared__ __align__(16) u16 Bu[2][128 * 32];
    __shared__ int   tokS[128];
    __shared__ float wtS[128];

    if (tid < 128) {
        const int pos = m0 + tid;
        const bool v = pos < cnt;
        tokS[tid] = v ? idx[e * TT + pos] : 0;
        wtS[tid]  = v ? wt[e * TT + pos] : 0.f;
    }
    __syncthreads();   // tokS visible; vmcnt drained -> pipeline starts at 0 outstanding

    // staging geometry: 512 threads x 16B = one 128x32 tile per issue; LDS dest linear,
    // source column XOR-swizzled so read chunk q^((row>>1)&3) returns global chunk q.
    const int srow = tid >> 2;                 // 0..127
    const int csw  = (((tid & 3) ^ ((srow >> 1) & 3))) * 8;
    const u16* pA = hs_b + (size_t)tokS[srow] * HH + csw;        // gathered token row
    const u16* pG = Wgt + ((size_t)e * II + n0 + srow) * HH + csw;
    const u16* pU = Wut + ((size_t)e * II + n0 + srow) * HH + csw;
    const int dofs = tid * 8;                  // == srow*32 + (tid&3)*8

    const int qx = (q ^ ((ln >> 1) & 3)) * 8;  // swizzled fragment-read chunk

    f32x4 accg[4][2], accu[4][2];
#pragma unroll
    for (int mi = 0; mi < 4; ++mi)
#pragma unroll
        for (int ni = 0; ni < 2; ++ni) { accg[mi][ni] = (f32x4)0.f; accu[mi][ni] = (f32x4)0.f; }

    // ---- 2-buffer counted-vmcnt pipeline over 64 K-tiles ----
    G1_STAGE(0, 0);
    int cur = 0;
    for (int t = 0; t < 63; ++t) {
        G1_STAGE(cur ^ 1, (t + 1) * 32);       // 6 outstanding / wave
        VM_WAIT(3);                            // tile t (issued last iter) landed
        __builtin_amdgcn_s_barrier();          // all waves' tile-t parts landed
        G1_COMPUTE(cur);
        IR_FENCE();
        __builtin_amdgcn_s_barrier();          // all waves done reading buf cur
        cur ^= 1;
    }
    VM_WAIT(0);
    __builtin_amdgcn_s_barrier();
    G1_COMPUTE(cur);                           // tile 63

    // epilogue: C/D layout col=lane&15, row=(lane>>4)*4+reg; pad rows have w=0 -> write 0
#pragma unroll
    for (int mi = 0; mi < 4; ++mi) {
#pragma unroll
        for (int r = 0; r < 4; ++r) {
            const int row = wr + mi * 16 + q * 4 + r;
            const float w = wtS[row];
#pragma unroll
            for (int ni = 0; ni < 2; ++ni) {
                const int i = n0 + wc + ni * 16 + ln;
                const float g = accg[mi][ni][r];
                const float u = accu[mi][ni][r];
                const float y = w * u * g / (1.f + __expf(-g));  // w * silu(g) * u
                act_g[(size_t)(off + m0 + row) * II + i] = f2bf(y);
            }
        }
    }
}

// ================= GEMM2 sparse (round-3 best): y_g[row] = act_g[row] @ Wd[e] =========
// 256 threads, tile 128x128, 2-buffer counted-vmcnt (4 loads/stage -> vmcnt(4)).
#define G2_COMPUTE(B) do { \
    __builtin_amdgcn_s_setprio(1); \
    bf16x8 af[4]; \
    _Pragma("unroll") \
    for (int mi = 0; mi < 4; ++mi) \
        af[mi] = *(const bf16x8*)&As[B][(wr + mi * 16 + ln) * 32 + qx]; \
    _Pragma("unroll") \
    for (int ni = 0; ni < 4; ++ni) { \
        bf16x8 bf = *(const bf16x8*)&Bs[B][(wc + ni * 16 + ln) * 32 + qx]; \
        _Pragma("unroll") \
        for (int mi = 0; mi < 4; ++mi) \
            acc[mi][ni] = __builtin_amdgcn_mfma_f32_16x16x32_bf16(af[mi], bf, acc[mi][ni], 0, 0, 0); \
    } \
    __builtin_amdgcn_s_setprio(0); \
} while (0)

#define G2_STAGE(B, KB) do { \
    __builtin_amdgcn_global_load_lds((gas1_t)(pA0 + (KB)), (las3_t)(&As[B][dofs]), 16, 0, 0); \
    __builtin_amdgcn_global_load_lds((gas1_t)(pA1 + (KB)), (las3_t)(&As[B][2048 + dofs]), 16, 0, 0); \
    __builtin_amdgcn_global_load_lds((gas1_t)(pB0 + (KB)), (las3_t)(&Bs[B][dofs]), 16, 0, 0); \
    __builtin_amdgcn_global_load_lds((gas1_t)(pB1 + (KB)), (las3_t)(&Bs[B][2048 + dofs]), 16, 0, 0); \
} while (0)

__global__ __launch_bounds__(256, 4)
void k_gemm2s(const u16* __restrict__ act_g,  // [MAXROWS, I] bf16
              const u16* __restrict__ Wdt,    // [E,H,I] bf16
              const int* __restrict__ meta,
              float* __restrict__ y_g) {      // [MAXROWS, H] f32
    const int e = blockIdx.x;
    const int pcnt = meta[8 + e];
    const int m0 = blockIdx.z * 128;
    if (m0 >= pcnt) return;
    const int n0 = blockIdx.y * 128;
    const int off = meta[e];
    const int tid = threadIdx.x;
    const int wave = tid >> 6, lane = tid & 63;
    const int ln = lane & 15, q = lane >> 4;
    const int wr = (wave >> 1) * 64, wc = (wave & 1) * 64;

    __shared__ __align__(16) u16 As[2][128 * 32];
    __shared__ __align__(16) u16 Bs[2][128 * 32];

    // staging: 256 threads x 16B = half tile per issue; 2 issues per tile.
    const int srow = tid >> 2;                 // 0..63 (+64 for second half; swizzle identical)
    const int csw  = (((tid & 3) ^ ((srow >> 1) & 3))) * 8;
    const u16* bA = act_g + (size_t)(off + m0) * II;
    const u16* bB = Wdt + ((size_t)e * HH + n0) * II;
    const u16* pA0 = bA + (size_t)srow * II + csw;
    const u16* pA1 = bA + (size_t)(srow + 64) * II + csw;
    const u16* pB0 = bB + (size_t)srow * II + csw;
    const u16* pB1 = bB + (size_t)(srow + 64) * II + csw;
    const int dofs = tid * 8;

    const int qx = (q ^ ((ln >> 1) & 3)) * 8;

    f32x4 acc[4][4];
#pragma unroll
    for (int mi = 0; mi < 4; ++mi)
#pragma unroll
        for (int ni = 0; ni < 4; ++ni) acc[mi][ni] = (f32x4)0.f;

    // ---- 2-buffer counted-vmcnt pipeline over 44 K-tiles ----
    G2_STAGE(0, 0);
    int cur = 0;
    for (int t = 0; t < 43; ++t) {
        G2_STAGE(cur ^ 1, (t + 1) * 32);       // 8 outstanding / wave
        VM_WAIT(4);                            // tile t landed
        __builtin_amdgcn_s_barrier();
        G2_COMPUTE(cur);
        IR_FENCE();
        __builtin_amdgcn_s_barrier();
        cur ^= 1;
    }
    VM_WAIT(0);
    __builtin_amdgcn_s_barrier();
    G2_COMPUTE(cur);                           // tile 43

    // plain stores; padded rows (garbage) never read by k_combine
#pragma unroll
    for (int mi = 0; mi < 4; ++mi) {
#pragma unroll
        for (int r = 0; r < 4; ++r) {
            const int row = wr + mi * 16 + q * 4 + r;
            float* dst = y_g + (size_t)(off + m0 + row) * HH + n0 + wc;
#pragma unroll
            for (int ni = 0; ni < 4; ++ni)
                dst[ni * 16 + ln] = acc[mi][ni][r];
        }
    }
}

// ---------- combine: out[t] = y_g[slot0(t)] + y_g[slot1(t)] (weights folded in GEMM1) ----
__global__ void k_combine(const float* __restrict__ y_g, const int* __restrict__ slot,
                          const int* __restrict__ meta, const int* __restrict__ flag,
                          void* __restrict__ out) {
    const int gid = blockIdx.x * 256 + threadIdx.x;
    const int t = gid >> 9;                 // 512 threads per token row (H/4)
    const int h = (gid & 511) * 4;
    const int s0 = slot[t * 2 + 0], s1 = slot[t * 2 + 1];
    const int r0 = meta[s0 >> 11] + (s0 & 2047);   // TT == 2048
    const int r1 = meta[s1 >> 11] + (s1 & 2047);
    const float4 a = *(const float4*)&y_g[(size_t)r0 * HH + h];
    const float4 b = *(const float4*)&y_g[(size_t)r1 * HH + h];
    const float4 v = make_float4(a.x + b.x, a.y + b.y, a.z + b.z, a.w + b.w);
    if (flag[0]) {
        *(float4*)((float*)out + (size_t)t * HH + h) = v;
    } else {
        u16* o = (u16*)out + (size_t)t * HH + h;
        o[0] = f2bf(v.x); o[1] = f2bf(v.y); o[2] = f2bf(v.z); o[3] = f2bf(v.w);
    }
}

// ---------- launch ----------
extern "C" void kernel_launch(void* const* d_in, const int* in_sizes, int n_in,
                              void* d_out, int out_size, void* d_ws, size_t ws_size,
                              hipStream_t stream) {
    (void)in_sizes; (void)n_in; (void)out_size;
    const void* hs     = d_in[0];   // [T,H]
    const void* logits = d_in[1];   // [T,E]
    const void* Wg     = d_in[2];   // [E,H,I]
    const void* Wu     = d_in[3];   // [E,H,I]
    const void* Wd     = d_in[4];   // [E,I,H]

    char* ws = (char*)d_ws;
    size_t off = 0;
    int*   flag   = (int*)(ws + off);   off += 256;
    int*   counts = (int*)(ws + off);   off += 256;
    int*   meta   = (int*)(ws + off);   off += 256;
    int*   idx    = (int*)(ws + off);   off += (size_t)EE * TT * 4;       // 64 KB
    float* wt     = (float*)(ws + off); off += (size_t)EE * TT * 4;       // 64 KB
    int*   slot   = (int*)(ws + off);   off += (size_t)TT * 2 * 4;        // 16 KB
    u16*   hs_b   = (u16*)(ws + off);   off += (size_t)TT * HH * 2;       // 8 MB
    u16*   Wgt    = (u16*)(ws + off);   off += (size_t)EE * II * HH * 2;  // 46 MB [E,I,H]
    u16*   Wut    = (u16*)(ws + off);   off += (size_t)EE * II * HH * 2;  // 46 MB [E,I,H]
    u16*   Wdt    = (u16*)(ws + off);   off += (size_t)EE * HH * II * 2;  // 46 MB [E,H,I]
    u16*   act_g  = (u16*)(ws + off);   off += (size_t)MAXROWS * II * 2;  // 14.4 MB
    float* y_g    = (float*)(ws + off); off += (size_t)MAXROWS * HH * 4;  // 42 MB
    if (ws_size < off) return;

    // 5 launches total: route, prep, gemm1, gemm2, combine
    k_route<<<dim3(1), dim3(1024), 0, stream>>>((const u16*)hs, logits, flag, counts,
                                                meta, idx, wt, slot);
    k_prep<<<dim3(CAST_BLOCKS + 24 * TR_BLOCKS), dim3(256), 0, stream>>>(
        hs, Wg, Wu, Wd, flag, hs_b, Wgt, Wut, Wdt);
    k_gemm1s<<<dim3(EE, II / 128, TT / 128), dim3(512), 0, stream>>>(hs_b, Wgt, Wut,
                                                counts, meta, idx, wt, act_g);
    k_gemm2s<<<dim3(EE, HH / 128, TT / 128), dim3(256), 0, stream>>>(act_g, Wdt, meta, y_g);
    k_combine<<<dim3(TT * HH / (256 * 4)), dim3(256), 0, stream>>>(y_g, slot, meta, flag, d_out);
}